// Round 2
// baseline (130.147 us; speedup 1.0000x reference)
//
#include <hip/hip_runtime.h>
#include <math.h>

#define NG 512
#define WI 256
#define HI 256
#define FXc 256.0f   // W / (2*tanfovx)
#define FYc 256.0f   // H / (2*tanfovy)
#define KCH 4        // gaussian chunks per pixel (parallelism on the composite chain)
#define GPC (NG/KCH) // 128 gaussians per chunk

#if __has_builtin(__builtin_amdgcn_exp2f)
#define EXP2F(x) __builtin_amdgcn_exp2f(x)
#else
#define EXP2F(x) exp2f(x)
#endif

// ---------------- kernel 1: fused preprocess + stable rank-sort ----------------
// One block of 512 threads. Each thread preprocesses gaussian g, keeps the
// 12-float record in registers, rank-sorts by tz via LDS keys, scatters the
// record to ws_s[rank]. Record layout (log2-domain conic, thr precomputed):
//   [mx, my, A2, B2,  C2, op, thr, colR,  colG, colB, tz, 0]
//   p = A2*dx^2 + C2*dy^2 + B2*dx*dy  (== power * log2(e))
//   valid <=> p <= 0 && p >= thr      (thr = -log2(255*op), +big if invisible)
__global__ __launch_bounds__(512) void gs_prep_sort(
    const float* __restrict__ means,
    const float* __restrict__ opac,
    const float* __restrict__ cols,
    const float* __restrict__ scales,
    const float* __restrict__ rots,
    const float* __restrict__ Vm,
    const float* __restrict__ Pm,
    float* __restrict__ ws_s,
    float* __restrict__ radii_out)
{
    __shared__ __align__(16) float key[NG];
    int g = threadIdx.x;

    // quaternion -> rotation
    float qr = rots[g*4+0], qx = rots[g*4+1], qy = rots[g*4+2], qz = rots[g*4+3];
    float inv = rsqrtf(qr*qr + qx*qx + qy*qy + qz*qz);
    qr *= inv; qx *= inv; qy *= inv; qz *= inv;
    float R00 = 1.f - 2.f*(qy*qy + qz*qz);
    float R01 = 2.f*(qx*qy - qr*qz);
    float R02 = 2.f*(qx*qz + qr*qy);
    float R10 = 2.f*(qx*qy + qr*qz);
    float R11 = 1.f - 2.f*(qx*qx + qz*qz);
    float R12 = 2.f*(qy*qz - qr*qx);
    float R20 = 2.f*(qx*qz - qr*qy);
    float R21 = 2.f*(qy*qz + qr*qx);
    float R22 = 1.f - 2.f*(qx*qx + qy*qy);

    float s0 = scales[g*3+0], s1 = scales[g*3+1], s2 = scales[g*3+2];
    float M00=R00*s0, M01=R01*s1, M02=R02*s2;
    float M10=R10*s0, M11=R11*s1, M12=R12*s2;
    float M20=R20*s0, M21=R21*s1, M22=R22*s2;

    float S00 = M00*M00 + M01*M01 + M02*M02;
    float S01 = M00*M10 + M01*M11 + M02*M12;
    float S02 = M00*M20 + M01*M21 + M02*M22;
    float S11 = M10*M10 + M11*M11 + M12*M12;
    float S12 = M10*M20 + M11*M21 + M12*M22;
    float S22 = M20*M20 + M21*M21 + M22*M22;

    float px = means[g*3+0], py = means[g*3+1], pz = means[g*3+2];
    float t0 = px*Vm[0] + py*Vm[4] + pz*Vm[8]  + Vm[12];
    float t1 = px*Vm[1] + py*Vm[5] + pz*Vm[9]  + Vm[13];
    float tz = px*Vm[2] + py*Vm[6] + pz*Vm[10] + Vm[14];
    float tzc = fmaxf(tz, 1e-4f);
    const float limx = 1.3f*0.5f, limy = 1.3f*0.5f;
    float txc = fminf(fmaxf(t0 / tzc, -limx), limx) * tzc;
    float tyc = fminf(fmaxf(t1 / tzc, -limy), limy) * tzc;

    float J00 = FXc / tzc;
    float J02 = -FXc * txc / (tzc * tzc);
    float J11 = FYc / tzc;
    float J12 = -FYc * tyc / (tzc * tzc);

    float Ta0 = J00*Vm[0] + J02*Vm[2];
    float Ta1 = J00*Vm[4] + J02*Vm[6];
    float Ta2 = J00*Vm[8] + J02*Vm[10];
    float Tb0 = J11*Vm[1] + J12*Vm[2];
    float Tb1 = J11*Vm[5] + J12*Vm[6];
    float Tb2 = J11*Vm[9] + J12*Vm[10];

    float u0 = Ta0*S00 + Ta1*S01 + Ta2*S02;
    float u1 = Ta0*S01 + Ta1*S11 + Ta2*S12;
    float u2 = Ta0*S02 + Ta1*S12 + Ta2*S22;
    float v0 = Tb0*S00 + Tb1*S01 + Tb2*S02;
    float v1 = Tb0*S01 + Tb1*S11 + Tb2*S12;
    float v2 = Tb0*S02 + Tb1*S12 + Tb2*S22;
    float c00 = u0*Ta0 + u1*Ta1 + u2*Ta2 + 0.3f;
    float c01 = u0*Tb0 + u1*Tb1 + u2*Tb2;
    float c11 = v0*Tb0 + v1*Tb1 + v2*Tb2 + 0.3f;

    float det = c00*c11 - c01*c01;
    float det_inv = 1.f / ((det != 0.f) ? det : 1.f);
    float Aa =  c11 * det_inv;
    float Bb = -c01 * det_inv;
    float Cc =  c00 * det_inv;

    float mid = 0.5f*(c00 + c11);
    float lam = mid + sqrtf(fmaxf(mid*mid - det, 0.1f));
    bool vis = (det > 0.f) && (tz > 0.2f);
    int rad = vis ? (int)ceilf(3.f*sqrtf(lam)) : 0;
    radii_out[g] = (float)rad;

    float h0 = px*Pm[0] + py*Pm[4] + pz*Pm[8]  + Pm[12];
    float h1 = px*Pm[1] + py*Pm[5] + pz*Pm[9]  + Pm[13];
    float h3 = px*Pm[3] + py*Pm[7] + pz*Pm[11] + Pm[15];
    float pw = 1.f / (h3 + 1e-7f);
    float mx = ((h0*pw + 1.f)*WI - 1.f)*0.5f;
    float my = ((h1*pw + 1.f)*HI - 1.f)*0.5f;

    float opv = vis ? opac[g] : 0.f;

    // fold -0.5, -B and log2(e) into the conic; precompute log2-domain threshold
    const float L2E = 1.4426950408889634f;
    float A2 = -0.5f*L2E*Aa;
    float B2 = -L2E*Bb;
    float C2 = -0.5f*L2E*Cc;
    float thr = (opv > 0.f) ? -log2f(255.f*opv) : 3.0e38f;

    key[g] = tz;
    __syncthreads();

    float k = key[g];
    int rank = 0;
    const float4* k4 = (const float4*)key;
    #pragma unroll 4
    for (int j = 0; j < NG/4; ++j) {
        float4 kk = k4[j];
        int j4 = j*4;
        rank += (kk.x < k) || ((kk.x == k) && (j4+0 < g));
        rank += (kk.y < k) || ((kk.y == k) && (j4+1 < g));
        rank += (kk.z < k) || ((kk.z == k) && (j4+2 < g));
        rank += (kk.w < k) || ((kk.w == k) && (j4+3 < g));
    }

    float4* dst = (float4*)(ws_s + rank*12);
    dst[0] = make_float4(mx, my, A2, B2);
    dst[1] = make_float4(C2, opv, thr, cols[g*3+0]);
    dst[2] = make_float4(cols[g*3+1], cols[g*3+2], tz, 0.f);
}

// ---------------- kernel 2: per-pixel blend, chunked composite chain ----------------
// Block = 256 threads = 64 pixels x 4 chunks (chunk is wave-uniform).
// Gaussian records read from GLOBAL with wave-uniform addresses -> compiler
// emits s_load (constant cache), freeing the LDS port and VALU address math.
__global__ __launch_bounds__(256) void gs_raster(
    const float* __restrict__ gs,
    const float* __restrict__ bg,
    float* __restrict__ out)
{
    int tx = threadIdx.x;
    int lane = tx & 63;
    int chunk = tx >> 6;                 // wave-uniform
    int pix = blockIdx.x * 64 + lane;
    float pxf = (float)(pix & (WI-1));
    float pyf = (float)(pix >> 8);

    const float* __restrict__ r = gs + chunk*GPC*12;
    float T = 1.f, cr = 0.f, cg = 0.f, cb = 0.f, dep = 0.f;
    #pragma unroll 4
    for (int g = 0; g < GPC; ++g) {
        float mx = r[0], my = r[1], A2 = r[2], B2 = r[3];
        float C2 = r[4], op = r[5], thr = r[6], k0 = r[7];
        float k1 = r[8], k2 = r[9], tz = r[10];
        r += 12;
        float dx = mx - pxf;
        float dy = my - pyf;
        float p = A2*(dx*dx) + C2*(dy*dy) + B2*(dx*dy);   // power * log2(e)
        float al = fminf(0.99f, op * EXP2F(p));
        bool valid = (p <= 0.f) && (p >= thr);
        al = valid ? al : 0.f;
        float w = al * T;
        cr  += w * k0;
        cg  += w * k1;
        cb  += w * k2;
        dep += w * tz;
        T = T - al * T;
    }

    // combine the 4 chunk-partials in depth order (Horner)
    __shared__ float part[KCH][64][5];   // stride 5 -> conflict-free epilogue
    part[chunk][lane][0] = cr;
    part[chunk][lane][1] = cg;
    part[chunk][lane][2] = cb;
    part[chunk][lane][3] = dep;
    part[chunk][lane][4] = T;
    __syncthreads();

    if (tx < 64) {
        float Cr = part[KCH-1][lane][0];
        float Cg = part[KCH-1][lane][1];
        float Cb = part[KCH-1][lane][2];
        float Dp = part[KCH-1][lane][3];
        float Tf = part[KCH-1][lane][4];
        #pragma unroll
        for (int c = KCH-2; c >= 0; --c) {
            float tc = part[c][lane][4];
            Cr = part[c][lane][0] + tc * Cr;
            Cg = part[c][lane][1] + tc * Cg;
            Cb = part[c][lane][2] + tc * Cb;
            Dp = part[c][lane][3] + tc * Dp;
            Tf = tc * Tf;
        }
        const int HW = WI * HI;
        int p = blockIdx.x * 64 + lane;
        out[p]        = Cr + Tf * bg[0];
        out[HW+p]     = Cg + Tf * bg[1];
        out[2*HW+p]   = Cb + Tf * bg[2];
        out[3*HW+p]   = Dp;
        out[4*HW+p]   = Tf;
    }
}

extern "C" void kernel_launch(void* const* d_in, const int* in_sizes, int n_in,
                              void* d_out, int out_size, void* d_ws, size_t ws_size,
                              hipStream_t stream)
{
    const float* means  = (const float*)d_in[0];
    const float* opac   = (const float*)d_in[1];
    const float* cols   = (const float*)d_in[2];
    const float* scales = (const float*)d_in[3];
    const float* rots   = (const float*)d_in[4];
    const float* bg     = (const float*)d_in[5];
    const float* Vm     = (const float*)d_in[6];
    const float* Pm     = (const float*)d_in[7];

    float* out  = (float*)d_out;
    float* ws_s = (float*)d_ws;                 // 12*NG floats, sorted packed records
    float* radii_out = out + 5*WI*HI;           // after color(3HW)+depth(HW)+Tfinal(HW)

    hipLaunchKernelGGL(gs_prep_sort, dim3(1), dim3(NG), 0, stream,
                       means, opac, cols, scales, rots, Vm, Pm, ws_s, radii_out);
    hipLaunchKernelGGL(gs_raster, dim3(WI*HI/64), dim3(256), 0, stream,
                       ws_s, bg, out);
}

// Round 3
// 102.265 us; speedup vs baseline: 1.2726x; 1.2726x over previous
//
#include <hip/hip_runtime.h>
#include <hip/hip_fp16.h>
#include <math.h>

#define NG 512
#define WI 256
#define HI 256
#define FXc 256.0f   // W / (2*tanfovx)
#define FYc 256.0f   // H / (2*tanfovy)
#define KCH 8        // depth chunks (one wave each)
#define GPC (NG/KCH) // 64 gaussians per chunk
#define P2MIN -7.9943534368588578f   // -log2(255): alpha>=1/255 test in log2 domain

#if __has_builtin(__builtin_amdgcn_exp2f)
#define EXP2F(x) __builtin_amdgcn_exp2f(x)
#else
#define EXP2F(x) exp2f(x)
#endif

// ---------------- kernel 1: fused preprocess + stable rank-sort ----------------
// Record per gaussian: 2 x float4 at ws_s + rank*8:
//   q0 = {mx, my, A2, B2}
//   q1 = {C2, lop, pack_f16(colR,colG), pack_f16(colB,tz)}
// p2 = A2*dx^2 + C2*dy^2 + B2*dx*dy + lop   (== power*log2e + log2(op))
// alpha = min(0.99, exp2(p2)); valid <=> p2 <= lop && p2 >= -log2(255)
// invisible gaussians: lop = -3e38 -> p2 ~ -3e38 -> invalid.
__global__ __launch_bounds__(512) void gs_prep_sort(
    const float* __restrict__ means,
    const float* __restrict__ opac,
    const float* __restrict__ cols,
    const float* __restrict__ scales,
    const float* __restrict__ rots,
    const float* __restrict__ Vm,
    const float* __restrict__ Pm,
    float* __restrict__ ws_s,
    float* __restrict__ radii_out)
{
    __shared__ __align__(16) float key[NG];
    int g = threadIdx.x;

    // quaternion -> rotation
    float qr = rots[g*4+0], qx = rots[g*4+1], qy = rots[g*4+2], qz = rots[g*4+3];
    float inv = rsqrtf(qr*qr + qx*qx + qy*qy + qz*qz);
    qr *= inv; qx *= inv; qy *= inv; qz *= inv;
    float R00 = 1.f - 2.f*(qy*qy + qz*qz);
    float R01 = 2.f*(qx*qy - qr*qz);
    float R02 = 2.f*(qx*qz + qr*qy);
    float R10 = 2.f*(qx*qy + qr*qz);
    float R11 = 1.f - 2.f*(qx*qx + qz*qz);
    float R12 = 2.f*(qy*qz - qr*qx);
    float R20 = 2.f*(qx*qz - qr*qy);
    float R21 = 2.f*(qy*qz + qr*qx);
    float R22 = 1.f - 2.f*(qx*qx + qy*qy);

    float s0 = scales[g*3+0], s1 = scales[g*3+1], s2 = scales[g*3+2];
    float M00=R00*s0, M01=R01*s1, M02=R02*s2;
    float M10=R10*s0, M11=R11*s1, M12=R12*s2;
    float M20=R20*s0, M21=R21*s1, M22=R22*s2;

    float S00 = M00*M00 + M01*M01 + M02*M02;
    float S01 = M00*M10 + M01*M11 + M02*M12;
    float S02 = M00*M20 + M01*M21 + M02*M22;
    float S11 = M10*M10 + M11*M11 + M12*M12;
    float S12 = M10*M20 + M11*M21 + M12*M22;
    float S22 = M20*M20 + M21*M21 + M22*M22;

    float px = means[g*3+0], py = means[g*3+1], pz = means[g*3+2];
    float t0 = px*Vm[0] + py*Vm[4] + pz*Vm[8]  + Vm[12];
    float t1 = px*Vm[1] + py*Vm[5] + pz*Vm[9]  + Vm[13];
    float tz = px*Vm[2] + py*Vm[6] + pz*Vm[10] + Vm[14];
    float tzc = fmaxf(tz, 1e-4f);
    const float limx = 1.3f*0.5f, limy = 1.3f*0.5f;
    float txc = fminf(fmaxf(t0 / tzc, -limx), limx) * tzc;
    float tyc = fminf(fmaxf(t1 / tzc, -limy), limy) * tzc;

    float J00 = FXc / tzc;
    float J02 = -FXc * txc / (tzc * tzc);
    float J11 = FYc / tzc;
    float J12 = -FYc * tyc / (tzc * tzc);

    float Ta0 = J00*Vm[0] + J02*Vm[2];
    float Ta1 = J00*Vm[4] + J02*Vm[6];
    float Ta2 = J00*Vm[8] + J02*Vm[10];
    float Tb0 = J11*Vm[1] + J12*Vm[2];
    float Tb1 = J11*Vm[5] + J12*Vm[6];
    float Tb2 = J11*Vm[9] + J12*Vm[10];

    float u0 = Ta0*S00 + Ta1*S01 + Ta2*S02;
    float u1 = Ta0*S01 + Ta1*S11 + Ta2*S12;
    float u2 = Ta0*S02 + Ta1*S12 + Ta2*S22;
    float v0 = Tb0*S00 + Tb1*S01 + Tb2*S02;
    float v1 = Tb0*S01 + Tb1*S11 + Tb2*S12;
    float v2 = Tb0*S02 + Tb1*S12 + Tb2*S22;
    float c00 = u0*Ta0 + u1*Ta1 + u2*Ta2 + 0.3f;
    float c01 = u0*Tb0 + u1*Tb1 + u2*Tb2;
    float c11 = v0*Tb0 + v1*Tb1 + v2*Tb2 + 0.3f;

    float det = c00*c11 - c01*c01;
    float det_inv = 1.f / ((det != 0.f) ? det : 1.f);
    float Aa =  c11 * det_inv;
    float Bb = -c01 * det_inv;
    float Cc =  c00 * det_inv;

    float mid = 0.5f*(c00 + c11);
    float lam = mid + sqrtf(fmaxf(mid*mid - det, 0.1f));
    bool vis = (det > 0.f) && (tz > 0.2f);
    int rad = vis ? (int)ceilf(3.f*sqrtf(lam)) : 0;
    radii_out[g] = (float)rad;

    float h0 = px*Pm[0] + py*Pm[4] + pz*Pm[8]  + Pm[12];
    float h1 = px*Pm[1] + py*Pm[5] + pz*Pm[9]  + Pm[13];
    float h3 = px*Pm[3] + py*Pm[7] + pz*Pm[11] + Pm[15];
    float pw = 1.f / (h3 + 1e-7f);
    float mx = ((h0*pw + 1.f)*WI - 1.f)*0.5f;
    float my = ((h1*pw + 1.f)*HI - 1.f)*0.5f;

    float opv = vis ? opac[g] : 0.f;

    const float L2E = 1.4426950408889634f;
    float A2 = -0.5f*L2E*Aa;
    float B2 = -L2E*Bb;
    float C2 = -0.5f*L2E*Cc;
    float lop = (opv > 0.f) ? log2f(opv) : -3.0e38f;

    // pack colors + tz as f16 pairs (error <= ~0.004, threshold 0.36)
    union { __half2 h; float f; } prg, pbt;
    prg.h = __halves2half2(__float2half_rn(cols[g*3+0]), __float2half_rn(cols[g*3+1]));
    pbt.h = __halves2half2(__float2half_rn(cols[g*3+2]), __float2half_rn(tz));

    key[g] = tz;
    __syncthreads();

    float k = key[g];
    int rank = 0;
    const float4* k4 = (const float4*)key;
    #pragma unroll 4
    for (int j = 0; j < NG/4; ++j) {
        float4 kk = k4[j];
        int j4 = j*4;
        rank += (kk.x < k) || ((kk.x == k) && (j4+0 < g));
        rank += (kk.y < k) || ((kk.y == k) && (j4+1 < g));
        rank += (kk.z < k) || ((kk.z == k) && (j4+2 < g));
        rank += (kk.w < k) || ((kk.w == k) && (j4+3 < g));
    }

    float4* dst = (float4*)(ws_s + rank*8);
    dst[0] = make_float4(mx, my, A2, B2);
    dst[1] = make_float4(C2, lop, prg.f, pbt.f);
}

// ---------------- kernel 2: raster — LDS-staged, 8 chunk-waves, 2 px/thread ----------------
// Block = 512 threads = 8 waves. Block covers 128 pixels of one row
// (row = blockIdx>>1, xbase = (blockIdx&1)*128). Wave c composites chunk c
// (64 gaussians) for all 128 pixels (lane handles x=xbase+lane, xbase+64+lane).
// Chunk partials combined depth-ordered (Horner) via LDS.
__global__ __launch_bounds__(512) void gs_raster(
    const float4* __restrict__ gsr,
    const float* __restrict__ bg,
    float* __restrict__ out)
{
    __shared__ __align__(16) float4 sg[NG*2];        // 16 KB: all records
    __shared__ float part[KCH*128*5];                // 20 KB: chunk partials

    int tx = threadIdx.x;
    sg[tx]       = gsr[tx];
    sg[tx + 512] = gsr[tx + 512];
    __syncthreads();

    int lane  = tx & 63;
    int chunk = tx >> 6;                 // wave-uniform
    int row   = blockIdx.x >> 1;
    int xb    = (blockIdx.x & 1) << 7;   // 0 or 128
    float px0 = (float)(xb + lane);
    float pyf = (float)row;

    const float4* r = sg + chunk * (GPC*2);
    float T0=1.f, cr0=0.f, cg0=0.f, cb0=0.f, dp0=0.f;
    float T1=1.f, cr1=0.f, cg1=0.f, cb1=0.f, dp1=0.f;

    #pragma unroll 4
    for (int g = 0; g < GPC; ++g) {
        float4 q0 = r[0];                // mx, my, A2, B2 (broadcast ds_read_b128)
        float4 q1 = r[1];                // C2, lop, rg16, bt16
        r += 2;
        float dy  = q0.y - pyf;
        float c1  = q0.w * dy;           // B2*dy
        float cy  = q1.x * dy;           // C2*dy
        float lop = q1.y;
        float c0  = fmaf(cy, dy, lop);   // C2*dy^2 + lop
        union { float f; __half2 h; } urg, ubt;
        urg.f = q1.z; ubt.f = q1.w;
        float colr = __low2float(urg.h), colg = __high2float(urg.h);
        float colb = __low2float(ubt.h), tzv  = __high2float(ubt.h);

        float dx0 = q0.x - px0;
        float p0  = fmaf(fmaf(q0.z, dx0, c1), dx0, c0);
        float a0  = fminf(0.99f, EXP2F(p0));
        a0 = ((p0 <= lop) && (p0 >= P2MIN)) ? a0 : 0.f;
        float w0 = a0 * T0;
        cr0 = fmaf(w0, colr, cr0);
        cg0 = fmaf(w0, colg, cg0);
        cb0 = fmaf(w0, colb, cb0);
        dp0 = fmaf(w0, tzv,  dp0);
        T0 -= w0;

        float dx1 = dx0 - 64.f;
        float p1  = fmaf(fmaf(q0.z, dx1, c1), dx1, c0);
        float a1  = fminf(0.99f, EXP2F(p1));
        a1 = ((p1 <= lop) && (p1 >= P2MIN)) ? a1 : 0.f;
        float w1 = a1 * T1;
        cr1 = fmaf(w1, colr, cr1);
        cg1 = fmaf(w1, colg, cg1);
        cb1 = fmaf(w1, colb, cb1);
        dp1 = fmaf(w1, tzv,  dp1);
        T1 -= w1;
    }

    // stash chunk partials: pixel index within block = lane (px0) and lane+64 (px1)
    int b0 = (chunk*128 + lane) * 5;     // stride 5 -> gcd(5,32)=1, conflict-free
    part[b0+0]=cr0; part[b0+1]=cg0; part[b0+2]=cb0; part[b0+3]=dp0; part[b0+4]=T0;
    int b1 = b0 + 64*5;
    part[b1+0]=cr1; part[b1+1]=cg1; part[b1+2]=cb1; part[b1+3]=dp1; part[b1+4]=T1;
    __syncthreads();

    // combine 8 depth-ordered chunk partials (Horner, back-to-front)
    if (tx < 128) {
        int t = tx;
        int e = ((KCH-1)*128 + t) * 5;
        float Cr = part[e+0], Cg = part[e+1], Cb = part[e+2], Dp = part[e+3], Tf = part[e+4];
        #pragma unroll
        for (int c = KCH-2; c >= 0; --c) {
            int o = (c*128 + t) * 5;
            float tc = part[o+4];
            Cr = part[o+0] + tc * Cr;
            Cg = part[o+1] + tc * Cg;
            Cb = part[o+2] + tc * Cb;
            Dp = part[o+3] + tc * Dp;
            Tf = tc * Tf;
        }
        const int HW = WI * HI;
        int p = row * WI + xb + t;
        out[p]        = Cr + Tf * bg[0];
        out[HW+p]     = Cg + Tf * bg[1];
        out[2*HW+p]   = Cb + Tf * bg[2];
        out[3*HW+p]   = Dp;
        out[4*HW+p]   = Tf;
    }
}

extern "C" void kernel_launch(void* const* d_in, const int* in_sizes, int n_in,
                              void* d_out, int out_size, void* d_ws, size_t ws_size,
                              hipStream_t stream)
{
    const float* means  = (const float*)d_in[0];
    const float* opac   = (const float*)d_in[1];
    const float* cols   = (const float*)d_in[2];
    const float* scales = (const float*)d_in[3];
    const float* rots   = (const float*)d_in[4];
    const float* bg     = (const float*)d_in[5];
    const float* Vm     = (const float*)d_in[6];
    const float* Pm     = (const float*)d_in[7];

    float* out  = (float*)d_out;
    float* ws_s = (float*)d_ws;                 // 8*NG floats, sorted packed records
    float* radii_out = out + 5*WI*HI;           // after color(3HW)+depth(HW)+Tfinal(HW)

    hipLaunchKernelGGL(gs_prep_sort, dim3(1), dim3(NG), 0, stream,
                       means, opac, cols, scales, rots, Vm, Pm, ws_s, radii_out);
    hipLaunchKernelGGL(gs_raster, dim3(HI*2), dim3(512), 0, stream,
                       (const float4*)ws_s, bg, out);
}

// Round 4
// 90.389 us; speedup vs baseline: 1.4399x; 1.1314x over previous
//
#include <hip/hip_runtime.h>
#include <hip/hip_fp16.h>
#include <math.h>

#define NG 512
#define WI 256
#define HI 256
#define FXc 256.0f   // W / (2*tanfovx)
#define FYc 256.0f   // H / (2*tanfovy)
#define P2MIN -7.9943534368588578f   // -log2(255)

#if __has_builtin(__builtin_amdgcn_exp2f)
#define EXP2F(x) __builtin_amdgcn_exp2f(x)
#else
#define EXP2F(x) exp2f(x)
#endif

// ---------------- kernel 1: fused preprocess + stable rank-sort + cull calc ----------------
// Record per gaussian (depth-sorted): 2 x float4 at ws_s + rank*8:
//   q0 = {mx, my, A2, B2}
//   q1 = {C2, lop, pack_f16(colR,colG), pack_f16(colB,tz)}
// p2 = A2*dx^2 + C2*dy^2 + B2*dx*dy + lop  (= power*log2e + log2(op))
// valid <=> p2 <= lop && p2 >= -log2(255)
// Cull record ws_cull[rank] = {my, ycull}: gaussian can affect row y only if
// |my - y| <= ycull (marginal-minimum bound, conservative => bit-exact output).
__global__ __launch_bounds__(512) void gs_prep_sort(
    const float* __restrict__ means,
    const float* __restrict__ opac,
    const float* __restrict__ cols,
    const float* __restrict__ scales,
    const float* __restrict__ rots,
    const float* __restrict__ Vm,
    const float* __restrict__ Pm,
    float* __restrict__ ws_s,
    float2* __restrict__ ws_cull,
    float* __restrict__ radii_out)
{
    __shared__ __align__(16) float key[NG];
    int g = threadIdx.x;

    // quaternion -> rotation
    float qr = rots[g*4+0], qx = rots[g*4+1], qy = rots[g*4+2], qz = rots[g*4+3];
    float inv = rsqrtf(qr*qr + qx*qx + qy*qy + qz*qz);
    qr *= inv; qx *= inv; qy *= inv; qz *= inv;
    float R00 = 1.f - 2.f*(qy*qy + qz*qz);
    float R01 = 2.f*(qx*qy - qr*qz);
    float R02 = 2.f*(qx*qz + qr*qy);
    float R10 = 2.f*(qx*qy + qr*qz);
    float R11 = 1.f - 2.f*(qx*qx + qz*qz);
    float R12 = 2.f*(qy*qz - qr*qx);
    float R20 = 2.f*(qx*qz - qr*qy);
    float R21 = 2.f*(qy*qz + qr*qx);
    float R22 = 1.f - 2.f*(qx*qx + qy*qy);

    float s0 = scales[g*3+0], s1 = scales[g*3+1], s2 = scales[g*3+2];
    float M00=R00*s0, M01=R01*s1, M02=R02*s2;
    float M10=R10*s0, M11=R11*s1, M12=R12*s2;
    float M20=R20*s0, M21=R21*s1, M22=R22*s2;

    float S00 = M00*M00 + M01*M01 + M02*M02;
    float S01 = M00*M10 + M01*M11 + M02*M12;
    float S02 = M00*M20 + M01*M21 + M02*M22;
    float S11 = M10*M10 + M11*M11 + M12*M12;
    float S12 = M10*M20 + M11*M21 + M12*M22;
    float S22 = M20*M20 + M21*M21 + M22*M22;

    float px = means[g*3+0], py = means[g*3+1], pz = means[g*3+2];
    float t0 = px*Vm[0] + py*Vm[4] + pz*Vm[8]  + Vm[12];
    float t1 = px*Vm[1] + py*Vm[5] + pz*Vm[9]  + Vm[13];
    float tz = px*Vm[2] + py*Vm[6] + pz*Vm[10] + Vm[14];
    float tzc = fmaxf(tz, 1e-4f);
    const float limx = 1.3f*0.5f, limy = 1.3f*0.5f;
    float txc = fminf(fmaxf(t0 / tzc, -limx), limx) * tzc;
    float tyc = fminf(fmaxf(t1 / tzc, -limy), limy) * tzc;

    float J00 = FXc / tzc;
    float J02 = -FXc * txc / (tzc * tzc);
    float J11 = FYc / tzc;
    float J12 = -FYc * tyc / (tzc * tzc);

    float Ta0 = J00*Vm[0] + J02*Vm[2];
    float Ta1 = J00*Vm[4] + J02*Vm[6];
    float Ta2 = J00*Vm[8] + J02*Vm[10];
    float Tb0 = J11*Vm[1] + J12*Vm[2];
    float Tb1 = J11*Vm[5] + J12*Vm[6];
    float Tb2 = J11*Vm[9] + J12*Vm[10];

    float u0 = Ta0*S00 + Ta1*S01 + Ta2*S02;
    float u1 = Ta0*S01 + Ta1*S11 + Ta2*S12;
    float u2 = Ta0*S02 + Ta1*S12 + Ta2*S22;
    float v0 = Tb0*S00 + Tb1*S01 + Tb2*S02;
    float v1 = Tb0*S01 + Tb1*S11 + Tb2*S12;
    float v2 = Tb0*S02 + Tb1*S12 + Tb2*S22;
    float c00 = u0*Ta0 + u1*Ta1 + u2*Ta2 + 0.3f;
    float c01 = u0*Tb0 + u1*Tb1 + u2*Tb2;
    float c11 = v0*Tb0 + v1*Tb1 + v2*Tb2 + 0.3f;

    float det = c00*c11 - c01*c01;
    float det_inv = 1.f / ((det != 0.f) ? det : 1.f);
    float Aa =  c11 * det_inv;
    float Bb = -c01 * det_inv;
    float Cc =  c00 * det_inv;

    float mid = 0.5f*(c00 + c11);
    float lam = mid + sqrtf(fmaxf(mid*mid - det, 0.1f));
    bool vis = (det > 0.f) && (tz > 0.2f);
    int rad = vis ? (int)ceilf(3.f*sqrtf(lam)) : 0;
    radii_out[g] = (float)rad;

    float h0 = px*Pm[0] + py*Pm[4] + pz*Pm[8]  + Pm[12];
    float h1 = px*Pm[1] + py*Pm[5] + pz*Pm[9]  + Pm[13];
    float h3 = px*Pm[3] + py*Pm[7] + pz*Pm[11] + Pm[15];
    float pw = 1.f / (h3 + 1e-7f);
    float mx = ((h0*pw + 1.f)*WI - 1.f)*0.5f;
    float my = ((h1*pw + 1.f)*HI - 1.f)*0.5f;

    float opv = vis ? opac[g] : 0.f;

    const float L2E = 1.4426950408889634f;
    float A2 = -0.5f*L2E*Aa;
    float B2 = -L2E*Bb;
    float C2 = -0.5f*L2E*Cc;
    float lop = (opv > 0.f) ? log2f(opv) : -3.0e38f;

    // --- conservative per-row cull bound ---
    // Q(dx,dy) = a*dx^2 + b*dx*dy + c*dy^2 = lop - p2 >= 0 (PD when det>0).
    // valid requires Q <= qmax := lop - P2MIN.
    // Q >= cmarg*dy^2 (min over dx) and Q >= amarg*dx^2 (min over dy).
    float a  = 0.5f*L2E*Aa;
    float c  = 0.5f*L2E*Cc;
    float b  = L2E*Bb;
    float qmax  = lop + 7.9943534368588578f;   // lop - P2MIN
    float cmarg = c - b*b/(4.f*a);
    float amarg = a - b*b/(4.f*c);
    float dxmin = fmaxf(0.f, fmaxf(-mx, mx - 255.f));   // dist from screen x-range
    bool alive = vis && (opv > 0.f) && (qmax >= 0.f) && (cmarg > 0.f)
                 && (amarg*dxmin*dxmin <= qmax);
    float ycull = alive ? sqrtf(qmax/cmarg) + 0.0625f : -1.f;

    union { __half2 h; float f; } prg, pbt;
    prg.h = __halves2half2(__float2half_rn(cols[g*3+0]), __float2half_rn(cols[g*3+1]));
    pbt.h = __halves2half2(__float2half_rn(cols[g*3+2]), __float2half_rn(tz));

    key[g] = tz;
    __syncthreads();

    float k = key[g];
    int rank = 0;
    const float4* k4 = (const float4*)key;
    #pragma unroll 4
    for (int j = 0; j < NG/4; ++j) {
        float4 kk = k4[j];
        int j4 = j*4;
        rank += (kk.x < k) || ((kk.x == k) && (j4+0 < g));
        rank += (kk.y < k) || ((kk.y == k) && (j4+1 < g));
        rank += (kk.z < k) || ((kk.z == k) && (j4+2 < g));
        rank += (kk.w < k) || ((kk.w == k) && (j4+3 < g));
    }

    float4* dst = (float4*)(ws_s + rank*8);
    dst[0] = make_float4(mx, my, A2, B2);
    dst[1] = make_float4(C2, lop, prg.f, pbt.f);
    ws_cull[rank] = make_float2(my, ycull);
}

// ---------------- kernel 2: raster with per-row culling ----------------
// One block (256 threads = 4 waves) per row. Compact the depth-sorted list to
// the gaussians whose support touches this row (ballot prefix-sum preserves
// order => exact compositing), stage them in LDS, then each thread blends its
// pixel over the ~n<<512 survivors via wave-uniform LDS broadcasts.
__global__ __launch_bounds__(256) void gs_raster(
    const float4* __restrict__ gsr,     // 2 float4 per gaussian, depth-sorted
    const float4* __restrict__ cullp,   // {my0,yc0,my1,yc1} per thread-pair
    const float* __restrict__ bg,
    float* __restrict__ out)
{
    __shared__ __align__(16) float4 cs[NG*2];   // compacted records (worst case 16 KB)
    __shared__ int wtot[4];

    int tx   = threadIdx.x;
    int lane = tx & 63;
    int wv   = tx >> 6;
    int y    = blockIdx.x;
    float yf = (float)y;

    // cull test for gaussians 2*tx and 2*tx+1 (coalesced float4 = 2 cull pairs)
    float4 cp = cullp[tx];
    bool f0 = fabsf(cp.x - yf) <= cp.y;
    bool f1 = fabsf(cp.z - yf) <= cp.w;

    unsigned long long m0 = __ballot(f0);
    unsigned long long m1 = __ballot(f1);
    unsigned long long lt = (lane == 63) ? 0x7fffffffffffffffULL : ((1ULL << lane) - 1ULL);
    lt = (1ULL << lane) - 1ULL;  // lane<64, shift by 63 max: ok
    int pre = __popcll(m0 & lt) + __popcll(m1 & lt);
    if (lane == 0) wtot[wv] = __popcll(m0) + __popcll(m1);
    __syncthreads();

    int base = 0, n = 0;
    #pragma unroll
    for (int w2 = 0; w2 < 4; ++w2) {
        int t = wtot[w2];
        base += (w2 < wv) ? t : 0;
        n += t;
    }

    int p0 = base + pre;
    if (f0) {
        cs[p0*2+0] = gsr[tx*4+0];
        cs[p0*2+1] = gsr[tx*4+1];
    }
    if (f1) {
        int p1 = p0 + (f0 ? 1 : 0);
        cs[p1*2+0] = gsr[tx*4+2];
        cs[p1*2+1] = gsr[tx*4+3];
    }
    __syncthreads();

    float pxf = (float)tx;
    float T = 1.f, cr = 0.f, cg = 0.f, cb = 0.f, dp = 0.f;
    for (int j = 0; j < n; ++j) {
        float4 q0 = cs[2*j+0];           // mx, my, A2, B2 (broadcast)
        float4 q1 = cs[2*j+1];           // C2, lop, rg16, bt16
        float dx = q0.x - pxf;
        float dy = q0.y - yf;
        float lop = q1.y;
        float p2 = fmaf(q0.z, dx*dx, fmaf(q1.x, dy*dy, fmaf(q0.w, dx*dy, lop)));
        float al = fminf(0.99f, EXP2F(p2));
        al = ((p2 <= lop) && (p2 >= P2MIN)) ? al : 0.f;
        float w = al * T;
        union { float f; __half2 h; } urg, ubt;
        urg.f = q1.z; ubt.f = q1.w;
        cr = fmaf(w, __low2float(urg.h),  cr);
        cg = fmaf(w, __high2float(urg.h), cg);
        cb = fmaf(w, __low2float(ubt.h),  cb);
        dp = fmaf(w, __high2float(ubt.h), dp);
        T -= w;
    }

    const int HW = WI * HI;
    int p = y * WI + tx;
    out[p]        = cr + T * bg[0];
    out[HW+p]     = cg + T * bg[1];
    out[2*HW+p]   = cb + T * bg[2];
    out[3*HW+p]   = dp;
    out[4*HW+p]   = T;
}

extern "C" void kernel_launch(void* const* d_in, const int* in_sizes, int n_in,
                              void* d_out, int out_size, void* d_ws, size_t ws_size,
                              hipStream_t stream)
{
    const float* means  = (const float*)d_in[0];
    const float* opac   = (const float*)d_in[1];
    const float* cols   = (const float*)d_in[2];
    const float* scales = (const float*)d_in[3];
    const float* rots   = (const float*)d_in[4];
    const float* bg     = (const float*)d_in[5];
    const float* Vm     = (const float*)d_in[6];
    const float* Pm     = (const float*)d_in[7];

    float* out  = (float*)d_out;
    float* ws_s = (float*)d_ws;                     // 8*NG floats, sorted records
    float2* ws_cull = (float2*)(ws_s + 8*NG);       // NG float2, sorted cull bounds
    float* radii_out = out + 5*WI*HI;

    hipLaunchKernelGGL(gs_prep_sort, dim3(1), dim3(NG), 0, stream,
                       means, opac, cols, scales, rots, Vm, Pm, ws_s, ws_cull, radii_out);
    hipLaunchKernelGGL(gs_raster, dim3(HI), dim3(WI), 0, stream,
                       (const float4*)ws_s, (const float4*)ws_cull, bg, out);
}

// Round 5
// 77.149 us; speedup vs baseline: 1.6870x; 1.1716x over previous
//
#include <hip/hip_runtime.h>
#include <hip/hip_fp16.h>
#include <math.h>

#define NG 512
#define WI 256
#define HI 256
#define FXc 256.0f   // W / (2*tanfovx)
#define FYc 256.0f   // H / (2*tanfovy)
#define P2MIN -7.9943534368588578f   // -log2(255)

#if __has_builtin(__builtin_amdgcn_exp2f)
#define EXP2F(x) __builtin_amdgcn_exp2f(x)
#else
#define EXP2F(x) exp2f(x)
#endif

// ---------------- single fused kernel: one block (256 thr) per image row ----------------
// Each block redundantly preprocesses ALL 512 gaussians (2 per thread, in
// registers), culls to the ~n<<512 whose support can touch this row
// (conservative marginal-min bound -> bit-exact), ballot-compacts survivors in
// original-index order, rank-sorts the n survivors by view depth tz
// (tie-break = slot index = original index, matching stable argsort), folds
// the per-row dy terms into the record, then each thread alpha-composites its
// pixel over the n sorted records via wave-uniform LDS broadcasts.
//
// Record math (log2 domain): p2 = A2*dx^2 + C2*dy^2 + B2*dx*dy + lop
//   alpha = min(0.99, exp2(p2)); valid <=> p2 <= lop && p2 >= -log2(255)
// Sorted, dy-folded record: s0 = {mx, A2, c1=B2*dy, c0=C2*dy^2+lop}
//                           s1 = {lop, f16x2(colR,colG), f16x2(colB,tz), 0}
//   p2 = (A2*dx + c1)*dx + c0
__global__ __launch_bounds__(256) void gs_fused(
    const float* __restrict__ means,
    const float* __restrict__ opac,
    const float* __restrict__ cols,
    const float* __restrict__ scales,
    const float* __restrict__ rots,
    const float* __restrict__ Vm,
    const float* __restrict__ Pm,
    const float* __restrict__ bg,
    float* __restrict__ out)
{
    __shared__ __align__(16) float4 us[NG*2];   // compacted survivors, index order (16 KB)
    __shared__ __align__(16) float4 cs[NG*2];   // depth-sorted, dy-folded (16 KB)
    __shared__ float skey[NG];                  // survivor tz keys
    __shared__ int wtot[4];

    int tx   = threadIdx.x;
    int lane = tx & 63;
    int wv   = tx >> 6;
    int y    = blockIdx.x;
    float yf = (float)y;

    // ---- phase 1: preprocess gaussians 2*tx and 2*tx+1 (registers only) ----
    float4 q0r[2], q1r[2];
    float tzs[2], myv[2], ycl[2], radf[2];

    #pragma unroll
    for (int i = 0; i < 2; ++i) {
        int g = 2*tx + i;

        float qr = rots[g*4+0], qx = rots[g*4+1], qy = rots[g*4+2], qz = rots[g*4+3];
        float inv = rsqrtf(qr*qr + qx*qx + qy*qy + qz*qz);
        qr *= inv; qx *= inv; qy *= inv; qz *= inv;
        float R00 = 1.f - 2.f*(qy*qy + qz*qz);
        float R01 = 2.f*(qx*qy - qr*qz);
        float R02 = 2.f*(qx*qz + qr*qy);
        float R10 = 2.f*(qx*qy + qr*qz);
        float R11 = 1.f - 2.f*(qx*qx + qz*qz);
        float R12 = 2.f*(qy*qz - qr*qx);
        float R20 = 2.f*(qx*qz - qr*qy);
        float R21 = 2.f*(qy*qz + qr*qx);
        float R22 = 1.f - 2.f*(qx*qx + qy*qy);

        float s0 = scales[g*3+0], s1 = scales[g*3+1], s2 = scales[g*3+2];
        float M00=R00*s0, M01=R01*s1, M02=R02*s2;
        float M10=R10*s0, M11=R11*s1, M12=R12*s2;
        float M20=R20*s0, M21=R21*s1, M22=R22*s2;

        float S00 = M00*M00 + M01*M01 + M02*M02;
        float S01 = M00*M10 + M01*M11 + M02*M12;
        float S02 = M00*M20 + M01*M21 + M02*M22;
        float S11 = M10*M10 + M11*M11 + M12*M12;
        float S12 = M10*M20 + M11*M21 + M12*M22;
        float S22 = M20*M20 + M21*M21 + M22*M22;

        float px = means[g*3+0], py = means[g*3+1], pz = means[g*3+2];
        float t0 = px*Vm[0] + py*Vm[4] + pz*Vm[8]  + Vm[12];
        float t1 = px*Vm[1] + py*Vm[5] + pz*Vm[9]  + Vm[13];
        float tz = px*Vm[2] + py*Vm[6] + pz*Vm[10] + Vm[14];
        float tzc = fmaxf(tz, 1e-4f);
        const float limx = 1.3f*0.5f, limy = 1.3f*0.5f;
        float txc = fminf(fmaxf(t0 / tzc, -limx), limx) * tzc;
        float tyc = fminf(fmaxf(t1 / tzc, -limy), limy) * tzc;

        float J00 = FXc / tzc;
        float J02 = -FXc * txc / (tzc * tzc);
        float J11 = FYc / tzc;
        float J12 = -FYc * tyc / (tzc * tzc);

        float Ta0 = J00*Vm[0] + J02*Vm[2];
        float Ta1 = J00*Vm[4] + J02*Vm[6];
        float Ta2 = J00*Vm[8] + J02*Vm[10];
        float Tb0 = J11*Vm[1] + J12*Vm[2];
        float Tb1 = J11*Vm[5] + J12*Vm[6];
        float Tb2 = J11*Vm[9] + J12*Vm[10];

        float u0 = Ta0*S00 + Ta1*S01 + Ta2*S02;
        float u1 = Ta0*S01 + Ta1*S11 + Ta2*S12;
        float u2 = Ta0*S02 + Ta1*S12 + Ta2*S22;
        float v0 = Tb0*S00 + Tb1*S01 + Tb2*S02;
        float v1 = Tb0*S01 + Tb1*S11 + Tb2*S12;
        float v2 = Tb0*S02 + Tb1*S12 + Tb2*S22;
        float c00 = u0*Ta0 + u1*Ta1 + u2*Ta2 + 0.3f;
        float c01 = u0*Tb0 + u1*Tb1 + u2*Tb2;
        float c11 = v0*Tb0 + v1*Tb1 + v2*Tb2 + 0.3f;

        float det = c00*c11 - c01*c01;
        float det_inv = 1.f / ((det != 0.f) ? det : 1.f);
        float Aa =  c11 * det_inv;
        float Bb = -c01 * det_inv;
        float Cc =  c00 * det_inv;

        float mid = 0.5f*(c00 + c11);
        float lam = mid + sqrtf(fmaxf(mid*mid - det, 0.1f));
        bool vis = (det > 0.f) && (tz > 0.2f);
        radf[i] = vis ? ceilf(3.f*sqrtf(lam)) : 0.f;

        float h0 = px*Pm[0] + py*Pm[4] + pz*Pm[8]  + Pm[12];
        float h1 = px*Pm[1] + py*Pm[5] + pz*Pm[9]  + Pm[13];
        float h3 = px*Pm[3] + py*Pm[7] + pz*Pm[11] + Pm[15];
        float pw = 1.f / (h3 + 1e-7f);
        float mx = ((h0*pw + 1.f)*WI - 1.f)*0.5f;
        float my = ((h1*pw + 1.f)*HI - 1.f)*0.5f;

        float opv = vis ? opac[g] : 0.f;

        const float L2E = 1.4426950408889634f;
        float A2 = -0.5f*L2E*Aa;
        float B2 = -L2E*Bb;
        float C2 = -0.5f*L2E*Cc;
        float lop = (opv > 0.f) ? log2f(opv) : -3.0e38f;

        // conservative cull: Q = lop - p2 >= 0 PD form; valid needs Q <= qmax.
        float a  = 0.5f*L2E*Aa;
        float c  = 0.5f*L2E*Cc;
        float b  = L2E*Bb;
        float qmax  = lop + 7.9943534368588578f;
        float cmarg = c - b*b/(4.f*a);
        float amarg = a - b*b/(4.f*c);
        float dxmin = fmaxf(0.f, fmaxf(-mx, mx - 255.f));
        bool alive = vis && (opv > 0.f) && (qmax >= 0.f) && (cmarg > 0.f)
                     && (amarg*dxmin*dxmin <= qmax);
        ycl[i] = alive ? sqrtf(qmax/cmarg) + 0.0625f : -1.f;

        union { __half2 h; float f; } prg, pbt;
        prg.h = __halves2half2(__float2half_rn(cols[g*3+0]), __float2half_rn(cols[g*3+1]));
        pbt.h = __halves2half2(__float2half_rn(cols[g*3+2]), __float2half_rn(tz));

        q0r[i] = make_float4(mx, my, A2, B2);
        q1r[i] = make_float4(C2, lop, prg.f, pbt.f);
        tzs[i] = tz;
        myv[i] = my;
    }

    // radii output (one block writes; others compute identically and skip)
    if (y == 0) {
        float* radii_out = out + 5*WI*HI;
        radii_out[2*tx]   = radf[0];
        radii_out[2*tx+1] = radf[1];
    }

    // ---- phase 2: cull + order-preserving ballot compaction into LDS ----
    bool f0 = fabsf(myv[0] - yf) <= ycl[0];
    bool f1 = fabsf(myv[1] - yf) <= ycl[1];

    unsigned long long m0 = __ballot(f0);
    unsigned long long m1 = __ballot(f1);
    unsigned long long lt = (1ULL << lane) - 1ULL;
    int pre = __popcll(m0 & lt) + __popcll(m1 & lt);
    if (lane == 0) wtot[wv] = __popcll(m0) + __popcll(m1);
    __syncthreads();

    int base = 0, n = 0;
    #pragma unroll
    for (int w2 = 0; w2 < 4; ++w2) {
        int t = wtot[w2];
        base += (w2 < wv) ? t : 0;
        n += t;
    }

    int p0 = base + pre;
    if (f0) {
        us[p0*2+0] = q0r[0];
        us[p0*2+1] = q1r[0];
        skey[p0]   = tzs[0];
    }
    if (f1) {
        int p1 = p0 + (f0 ? 1 : 0);
        us[p1*2+0] = q0r[1];
        us[p1*2+1] = q1r[1];
        skey[p1]   = tzs[1];
    }
    __syncthreads();

    // ---- phase 3: rank-sort n survivors by tz (stable via slot index) ----
    // and fold per-row dy into the record.
    if (tx < n) {
        float k = skey[tx];
        int rank = 0;
        for (int j = 0; j < n; ++j) {
            float o = skey[j];
            rank += (o < k) || ((o == k) && (j < tx));
        }
        float4 a = us[2*tx+0];   // mx, my, A2, B2
        float4 b = us[2*tx+1];   // C2, lop, rg16, bt16
        float dy = a.y - yf;
        float c1 = a.w * dy;                  // B2*dy
        float c0 = fmaf(b.x*dy, dy, b.y);     // C2*dy^2 + lop
        cs[2*rank+0] = make_float4(a.x, a.z, c1, c0);
        cs[2*rank+1] = make_float4(b.y, b.z, b.w, 0.f);
    }
    __syncthreads();

    // ---- phase 4: front-to-back blend over sorted survivors ----
    float pxf = (float)tx;
    float T = 1.f, cr = 0.f, cg = 0.f, cb = 0.f, dp = 0.f;
    for (int j = 0; j < n; ++j) {
        float4 a = cs[2*j+0];    // mx, A2, c1, c0  (wave-uniform broadcast)
        float4 b = cs[2*j+1];    // lop, rg16, bt16, 0
        float dx = a.x - pxf;
        float p2 = fmaf(fmaf(a.y, dx, a.z), dx, a.w);
        float al = fminf(0.99f, EXP2F(p2));
        al = ((p2 <= b.x) && (p2 >= P2MIN)) ? al : 0.f;
        float w = al * T;
        union { float f; __half2 h; } urg, ubt;
        urg.f = b.y; ubt.f = b.z;
        cr = fmaf(w, __low2float(urg.h),  cr);
        cg = fmaf(w, __high2float(urg.h), cg);
        cb = fmaf(w, __low2float(ubt.h),  cb);
        dp = fmaf(w, __high2float(ubt.h), dp);
        T -= w;
    }

    const int HW = WI * HI;
    int p = y * WI + tx;
    out[p]        = cr + T * bg[0];
    out[HW+p]     = cg + T * bg[1];
    out[2*HW+p]   = cb + T * bg[2];
    out[3*HW+p]   = dp;
    out[4*HW+p]   = T;
}

extern "C" void kernel_launch(void* const* d_in, const int* in_sizes, int n_in,
                              void* d_out, int out_size, void* d_ws, size_t ws_size,
                              hipStream_t stream)
{
    const float* means  = (const float*)d_in[0];
    const float* opac   = (const float*)d_in[1];
    const float* cols   = (const float*)d_in[2];
    const float* scales = (const float*)d_in[3];
    const float* rots   = (const float*)d_in[4];
    const float* bg     = (const float*)d_in[5];
    const float* Vm     = (const float*)d_in[6];
    const float* Pm     = (const float*)d_in[7];

    float* out = (float*)d_out;

    hipLaunchKernelGGL(gs_fused, dim3(HI), dim3(WI), 0, stream,
                       means, opac, cols, scales, rots, Vm, Pm, bg, out);
}